// Round 1
// baseline (403.405 us; speedup 1.0000x reference)
//
#include <hip/hip_runtime.h>

// CrossMerge3D: out[b,c,i,j,k] = (sum of 12 scan contributions)/12
// B=2, S=12, C=96, D=32, N=32768.
// group-i (s=0..3):  n = i*1024 + j*32 + k ; terms y0[n]+y1[n]+y2[N-1-n]+y3[N-1-n]
// group-j (s=4..7):  n = j*1024 + k*32 + i ; terms y4[n]+y5[n]+y6[N-1-n]+y7[N-1-n]
// group-k (s=8..11): n = k*1024 + i*32 + j ; terms y8[n]+y9[n]+y10[N-1-n]+y11[N-1-n]
//
// Strategy: 1 block per (b,c) slice. Each group is read in ITS OWN layout
// (fully coalesced, every 128B line consumed exactly once), accumulated into a
// padded full-volume LDS tile; final phase adds group-i and stores coalesced.

#define C_ 96
#define D_ 32
#define N_ 32768
#define SCAN_STRIDE ((size_t)C_ * N_)

// LDS strides chosen so that stride mod 32 == 1 for every dimension:
// k: 1, j: 33, i: 33*32+1 = 1057  -> conflict-free for all three phase mappings.
#define J_STR 33
#define I_STR 1057
#define LDS_FLOATS (31 * I_STR + 31 * J_STR + 31 + 1)  // 33822 -> 135288 bytes

__global__ void __launch_bounds__(1024, 1)
cross_merge3d_kernel(const float* __restrict__ ys, float* __restrict__ out) {
    extern __shared__ float lds[];

    const int bc = blockIdx.x;       // 0..191
    const int b  = bc / C_;
    const int c  = bc % C_;
    const float* y = ys + ((size_t)b * 12 * C_ + c) * (size_t)N_;
    const int t = threadIdx.x;

    // ---- Phase 1: group-j (scans 4..7), source layout (j,k,i): contiguous in i
    {
        const float* y4 = y + 4 * SCAN_STRIDE;
        const float* y5 = y + 5 * SCAN_STRIDE;
        const float* y6 = y + 6 * SCAN_STRIDE;
        const float* y7 = y + 7 * SCAN_STRIDE;
        const int ii = t & 31;          // contiguous across lanes -> coalesced
        const int kk = (t >> 5) & 31;
        #pragma unroll 4
        for (int jj = 0; jj < 32; ++jj) {
            const int n = jj * 1024 + kk * 32 + ii;
            const int r = N_ - 1 - n;
            const float s = y4[n] + y5[n] + y6[r] + y7[r];
            lds[ii * I_STR + jj * J_STR + kk] = s;   // first write, no zero-init needed
        }
    }
    __syncthreads();

    // ---- Phase 2: group-k (scans 8..11), source layout (k,i,j): contiguous in j
    {
        const float* y8  = y + 8  * SCAN_STRIDE;
        const float* y9  = y + 9  * SCAN_STRIDE;
        const float* y10 = y + 10 * SCAN_STRIDE;
        const float* y11 = y + 11 * SCAN_STRIDE;
        const int jj = t & 31;          // contiguous across lanes -> coalesced
        const int ii = (t >> 5) & 31;
        #pragma unroll 4
        for (int kk = 0; kk < 32; ++kk) {
            const int n = kk * 1024 + ii * 32 + jj;
            const int r = N_ - 1 - n;
            const float s = y8[n] + y9[n] + y10[r] + y11[r];
            lds[ii * I_STR + jj * J_STR + kk] += s;
        }
    }
    __syncthreads();

    // ---- Phase 3: group-i (scans 0..3) + write out, layout (i,j,k): contiguous in k
    {
        const float* y0 = y;
        const float* y1 = y + 1 * SCAN_STRIDE;
        const float* y2 = y + 2 * SCAN_STRIDE;
        const float* y3 = y + 3 * SCAN_STRIDE;
        float* o = out + ((size_t)b * C_ + c) * (size_t)N_;
        const int kk = t & 31;          // contiguous across lanes -> coalesced
        const int jj = (t >> 5) & 31;
        #pragma unroll 4
        for (int ii = 0; ii < 32; ++ii) {
            const int n = ii * 1024 + jj * 32 + kk;
            const int r = N_ - 1 - n;
            const float s = y0[n] + y1[n] + y2[r] + y3[r];
            o[n] = (s + lds[ii * I_STR + jj * J_STR + kk]) * (1.0f / 12.0f);
        }
    }
}

extern "C" void kernel_launch(void* const* d_in, const int* in_sizes, int n_in,
                              void* d_out, int out_size, void* d_ws, size_t ws_size,
                              hipStream_t stream) {
    (void)in_sizes; (void)n_in; (void)d_ws; (void)ws_size; (void)out_size;
    const float* ys = (const float*)d_in[0];
    float* out = (float*)d_out;

    const size_t lds_bytes = (size_t)LDS_FLOATS * sizeof(float);
    static bool attr_set = false;  // idempotent host-side attribute; safe under capture
    hipFuncSetAttribute(reinterpret_cast<const void*>(&cross_merge3d_kernel),
                        hipFuncAttributeMaxDynamicSharedMemorySize, (int)lds_bytes);

    dim3 grid(2 * C_);   // 192 blocks: one per (b,c)
    dim3 block(1024);
    cross_merge3d_kernel<<<grid, block, lds_bytes, stream>>>(ys, out);
}

// Round 3
// 401.952 us; speedup vs baseline: 1.0036x; 1.0036x over previous
//
#include <hip/hip_runtime.h>

// CrossMerge3D: out[b,c,i,j,k] = (sum of 12 scan contributions)/12
// B=2, S=12, C=96, D=32, N=32768.
// group-i (s=0..3):  n = i*1024 + j*32 + k ; y0[n]+y1[n]+y2[N-1-n]+y3[N-1-n]
// group-j (s=4..7):  n = j*1024 + k*32 + i ; y4[n]+y5[n]+y6[N-1-n]+y7[N-1-n]
// group-k (s=8..11): n = k*1024 + i*32 + j ; y8[n]+y9[n]+y10[N-1-n]+y11[N-1-n]
//
// 1 block per (b,c) slice. Each group read in ITS OWN layout with float4
// (16B/lane) fully-coalesced loads; flipped scans load the mirrored float4 at
// 8191-v and reverse components. Accumulate in a padded full-volume LDS tile
// (strides 1/33/1057, all ==1 mod 32 -> <=2-way banks in every phase = free).

#define C_ 96
#define D_ 32
#define N_ 32768
#define SCAN_STRIDE ((size_t)C_ * N_)

#define J_STR 33
#define I_STR 1057
#define LDS_FLOATS (31 * I_STR + 31 * J_STR + 31 + 1)  // 33822 -> 135288 bytes

__global__ void __launch_bounds__(1024, 1)
cross_merge3d_kernel(const float* __restrict__ ys, float* __restrict__ out) {
    extern __shared__ float lds[];

    const int bc = blockIdx.x;       // 0..191
    const int b  = bc / C_;
    const int c  = bc % C_;
    const float* y = ys + ((size_t)b * 12 * C_ + c) * (size_t)N_;
    const int t   = threadIdx.x;
    const int q   = t & 7;           // float4 slot within a 32-float row
    const int mid = (t >> 3) & 31;
    const int hi  = t >> 8;          // 0..3

    // ---- Phase 1: group-j (scans 4..7), source fast dim = i
    {
        const float4* y4 = (const float4*)(y + 4 * SCAN_STRIDE);
        const float4* y5 = (const float4*)(y + 5 * SCAN_STRIDE);
        const float4* y6 = (const float4*)(y + 6 * SCAN_STRIDE);
        const float4* y7 = (const float4*)(y + 7 * SCAN_STRIDE);
        const int kk = mid;
        #pragma unroll 2
        for (int it = 0; it < 8; ++it) {
            const int jj = hi + 4 * it;
            const int v  = jj * 256 + kk * 8 + q;     // n0/4, n0 = jj*1024+kk*32+4q
            const float4 f0 = y4[v];
            const float4 f1 = y5[v];
            const float4 r0 = y6[8191 - v];           // mirrored float4, reversed elems
            const float4 r1 = y7[8191 - v];
            const float s0 = f0.x + f1.x + r0.w + r1.w;
            const float s1 = f0.y + f1.y + r0.z + r1.z;
            const float s2 = f0.z + f1.z + r0.y + r1.y;
            const float s3 = f0.w + f1.w + r0.x + r1.x;
            float* p = &lds[(4 * q) * I_STR + jj * J_STR + kk];   // ii = 4q+e
            p[0 * I_STR] = s0;
            p[1 * I_STR] = s1;
            p[2 * I_STR] = s2;
            p[3 * I_STR] = s3;
        }
    }
    __syncthreads();

    // ---- Phase 2: group-k (scans 8..11), source fast dim = j
    {
        const float4* y8  = (const float4*)(y + 8  * SCAN_STRIDE);
        const float4* y9  = (const float4*)(y + 9  * SCAN_STRIDE);
        const float4* y10 = (const float4*)(y + 10 * SCAN_STRIDE);
        const float4* y11 = (const float4*)(y + 11 * SCAN_STRIDE);
        const int ii = mid;
        #pragma unroll 2
        for (int it = 0; it < 8; ++it) {
            const int kk = hi + 4 * it;
            const int v  = kk * 256 + ii * 8 + q;     // n0 = kk*1024+ii*32+4q (jj fast)
            const float4 f0 = y8[v];
            const float4 f1 = y9[v];
            const float4 r0 = y10[8191 - v];
            const float4 r1 = y11[8191 - v];
            const float s0 = f0.x + f1.x + r0.w + r1.w;
            const float s1 = f0.y + f1.y + r0.z + r1.z;
            const float s2 = f0.z + f1.z + r0.y + r1.y;
            const float s3 = f0.w + f1.w + r0.x + r1.x;
            float* p = &lds[ii * I_STR + (4 * q) * J_STR + kk];   // jj = 4q+e
            p[0 * J_STR] += s0;
            p[1 * J_STR] += s1;
            p[2 * J_STR] += s2;
            p[3 * J_STR] += s3;
        }
    }
    __syncthreads();

    // ---- Phase 3: group-i (scans 0..3) + output, fast dim = k
    {
        const float4* y0 = (const float4*)(y + 0 * SCAN_STRIDE);
        const float4* y1 = (const float4*)(y + 1 * SCAN_STRIDE);
        const float4* y2 = (const float4*)(y + 2 * SCAN_STRIDE);
        const float4* y3 = (const float4*)(y + 3 * SCAN_STRIDE);
        float4* o4 = (float4*)(out + ((size_t)b * C_ + c) * (size_t)N_);
        const int jj = mid;
        #pragma unroll 2
        for (int it = 0; it < 8; ++it) {
            const int ii = hi + 4 * it;
            const int v  = ii * 256 + jj * 8 + q;     // n0 = ii*1024+jj*32+4q (kk fast)
            const float4 f0 = y0[v];
            const float4 f1 = y1[v];
            const float4 r0 = y2[8191 - v];
            const float4 r1 = y3[8191 - v];
            const float* p = &lds[ii * I_STR + jj * J_STR + 4 * q];  // kk = 4q+e, contiguous
            float4 res;
            res.x = (f0.x + f1.x + r0.w + r1.w + p[0]) * (1.0f / 12.0f);
            res.y = (f0.y + f1.y + r0.z + r1.z + p[1]) * (1.0f / 12.0f);
            res.z = (f0.z + f1.z + r0.y + r1.y + p[2]) * (1.0f / 12.0f);
            res.w = (f0.w + f1.w + r0.x + r1.x + p[3]) * (1.0f / 12.0f);
            o4[v] = res;
        }
    }
}

extern "C" void kernel_launch(void* const* d_in, const int* in_sizes, int n_in,
                              void* d_out, int out_size, void* d_ws, size_t ws_size,
                              hipStream_t stream) {
    (void)in_sizes; (void)n_in; (void)d_ws; (void)ws_size; (void)out_size;
    const float* ys = (const float*)d_in[0];
    float* out = (float*)d_out;

    const size_t lds_bytes = (size_t)LDS_FLOATS * sizeof(float);
    hipFuncSetAttribute(reinterpret_cast<const void*>(&cross_merge3d_kernel),
                        hipFuncAttributeMaxDynamicSharedMemorySize, (int)lds_bytes);

    dim3 grid(2 * C_);   // 192 blocks: one per (b,c)
    dim3 block(1024);
    cross_merge3d_kernel<<<grid, block, lds_bytes, stream>>>(ys, out);
}